// Round 12
// baseline (227.819 us; speedup 1.0000x reference)
//
#include <hip/hip_runtime.h>
#include <math.h>

#define BATCH 8
#define CH    256
#define HWN   4096
#define DQK   16

typedef __attribute__((ext_vector_type(8))) short short8;
typedef __attribute__((ext_vector_type(4))) float float4v;

#define L2E 1.4426950408889634f

__device__ __forceinline__ unsigned short f2bf(float f) {
    union { float f; unsigned int u; } v; v.f = f;
    unsigned int r = v.u + 0x7FFF + ((v.u >> 16) & 1);   // RNE
    return (unsigned short)(r >> 16);
}
// HW packed f32->bf16 convert (RNE): %1 -> low16, %2 -> high16
__device__ __forceinline__ unsigned int cvtpk(float lo, float hi) {
    unsigned int r;
    asm("v_cvt_pk_bf16_f32 %0, %1, %2" : "=v"(r) : "v"(lo), "v"(hi));
    return r;
}
// 2^x via hardware v_exp_f32, compiler-managed TRANS hazards
__device__ __forceinline__ float ex2(float x) {
#if __has_builtin(__builtin_amdgcn_exp2f)
    return __builtin_amdgcn_exp2f(x);
#else
    return exp2f(x);
#endif
}
// Block barrier WITHOUT the vmcnt(0) drain __syncthreads carries (T4):
// only LDS ordering is required for the pB exchange; global prefetches
// stay in flight across the barrier.
__device__ __forceinline__ void lds_barrier() {
    asm volatile("s_waitcnt lgkmcnt(0)" ::: "memory");
    __builtin_amdgcn_s_barrier();
}
// ft row permutation: stored row s holds key m with s4=m2, s3=m4, s2=m3
// (bits 0,1,5+ unchanged). Makes S^T output registers align with PV B-frag
// slots in the SAME lane (no cross-lane transpose needed).
__device__ __forceinline__ int perm_ft(int m) {
    return (m & ~28) | ((m & 24) >> 1) | ((m & 4) << 2);
}

// ---------------- kernel 0: W_cat -> bf16, biases -> bcat ----------------
__global__ __launch_bounds__(256) void wcast_kernel(
    const float* __restrict__ Wf, const float* __restrict__ bf_,
    const float* __restrict__ Wg, const float* __restrict__ bg,
    const float* __restrict__ Wh, const float* __restrict__ bh,
    unsigned short* __restrict__ Wbf, float* __restrict__ bcat)
{
    const int r = blockIdx.x;   // 288 rows
    const int t = threadIdx.x;  // 256 cols
    const float* src = (r < 16) ? (Wf + r*CH) : (r < 32) ? (Wg + (r-16)*CH) : (Wh + (r-32)*CH);
    Wbf[r*CH + t] = f2bf(src[t]);
    if (t == 0) bcat[r] = (r < 16) ? bf_[r] : (r < 32) ? bg[r-16] : bh[r-32];
}

// ---------------- kernel 1: FUSED transpose + MFMA projection ----------------
// R11 design (kept): kills the xt tensor. Block = 32 px x 256 c, grid
// (128, 8) = 1024 blocks (4/CU). Stage x[b][*][px0..31] -> LDS tile[32][264]
// bf16 (float4 loads over px, cvt_pk; rows 16B-aligned). One barrier.
// Wave split covers all 18 W_cat rows in one pass over x:
//   wave w: rt-group (w>>1)*9, px-half (w&1)*16. acc 9x4 = 36 AGPR.
// Epilogue: ft at perm_ft rows PRE-SCALED by log2e; g; h3 frag layout.
__global__ __launch_bounds__(256, 4) void proj_kernel(
    const float* __restrict__ x, const unsigned short* __restrict__ Wbf,
    const float* __restrict__ bcat,
    unsigned short* __restrict__ ft, unsigned short* __restrict__ g,
    unsigned short* __restrict__ h3)
{
    const int t    = threadIdx.x;
    const int px0  = blockIdx.x * 32;
    const int b    = blockIdx.y;
    const int lane = t & 63, w = t >> 6, l15 = lane & 15, quad = lane >> 4;
    const int rtbase = (w >> 1) * 9;      // 0 or 9
    const int pxh    = (w & 1) * 16;      // px-half within the 32-px tile

    __shared__ unsigned short tile[32][264];   // 16.5 KB, rows 16B-aligned

    // ---- stage: x[b][c][px0+px4 .. +3] -> tile[px][c] ----
    const int px4 = (t & 7) * 4;          // 0..28
    const int c0  = t >> 3;               // 0..31
    #pragma unroll
    for (int j = 0; j < 8; j++) {
        int c = c0 + j*32;
        float4 v = *(const float4*)&x[(size_t)(b*CH + c)*HWN + px0 + px4];
        unsigned int u01 = cvtpk(v.x, v.y), u23 = cvtpk(v.z, v.w);
        tile[px4+0][c] = (unsigned short)u01;
        tile[px4+1][c] = (unsigned short)(u01 >> 16);
        tile[px4+2][c] = (unsigned short)u23;
        tile[px4+3][c] = (unsigned short)(u23 >> 16);
    }
    __syncthreads();

    float4v acc[9];
    #pragma unroll
    for (int rt = 0; rt < 9; rt++) acc[rt] = (float4v){0.f,0.f,0.f,0.f};

    const unsigned short* wrow = &Wbf[(size_t)l15*CH + quad*8];

    #pragma unroll
    for (int ks = 0; ks < 8; ks++) {
        short8 afrag = *(const short8*)&tile[pxh + l15][quad*8 + ks*32];
        #pragma unroll
        for (int rt = 0; rt < 9; rt++) {
            short8 bfrag = *(const short8*)&wrow[(size_t)(rtbase + rt)*16*CH + ks*32];
            acc[rt] = __builtin_amdgcn_mfma_f32_16x16x32_bf16(afrag, bfrag, acc[rt], 0, 0, 0);
        }
    }

    const int pxl = px0 + pxh + quad*4;   // this lane's px base (+r)
    const int mt  = px0 >> 5;             // = blockIdx.x
    const int sub = ((w & 1)*2 + (quad >> 1))*128 + l15*8 + (quad & 1)*4;
    #pragma unroll
    for (int rt = 0; rt < 9; rt++) {
        const int R = rtbase + rt;        // uniform per wave
        if (R == 0) {                     // -> ft at perm_ft rows, * log2e
            float bv = bcat[l15];
            const int s0 = perm_ft(pxl);  // r only touches bits 0,1
            unsigned int p01 = cvtpk((acc[rt][0] + bv)*L2E, (acc[rt][1] + bv)*L2E);
            unsigned int p23 = cvtpk((acc[rt][2] + bv)*L2E, (acc[rt][3] + bv)*L2E);
            unsigned short* fp0 = &ft[((size_t)b*HWN + s0)*32];
            fp0[l15]       = (unsigned short)p01;         fp0[16 + l15]  = 0;
            fp0[32 + l15]  = (unsigned short)(p01 >> 16); fp0[48 + l15]  = 0;
            fp0[64 + l15]  = (unsigned short)p23;         fp0[80 + l15]  = 0;
            fp0[96 + l15]  = (unsigned short)(p23 >> 16); fp0[112 + l15] = 0;
        } else if (R == 1) {              // -> g (4 consecutive px: uint2)
            float bv = bcat[16 + l15];
            unsigned int a01 = cvtpk(acc[rt][0] + bv, acc[rt][1] + bv);
            unsigned int a23 = cvtpk(acc[rt][2] + bv, acc[rt][3] + bv);
            *(uint2*)&g[(size_t)(b*DQK + l15)*HWN + pxl] = make_uint2(a01, a23);
        } else {                          // -> h3 frag layout
            float bv = bcat[R*16 + l15];
            unsigned int u0 = cvtpk(acc[rt][0] + bv, acc[rt][1] + bv);
            unsigned int u1 = cvtpk(acc[rt][2] + bv, acc[rt][3] + bv);
            *(uint2*)&h3[(((size_t)((b*128 + mt)*16 + (R-2))) << 9) + sub] = make_uint2(u0, u1);
        }
    }
}

// ---------------- kernel 2: MFMA flash attention, 8 waves ----------------
// R7 structure (best measured: 86.0 us, VGPR 60, no spill); R12 change is
// ONLY the main-loop quad-unroll: 4 ATTN_STEP bodies per trip make all
// tile indices compile-time offsets from one runtime base -> compiler
// strength-reduces the 6 per-iter global addresses (hr x4, fr x2) and
// hoists the 2 pB write addresses. Dataflow/barriers/buffers identical.
// Session lessons: >96 live VGPRs spills (R3/R8/R9); LDS->L2 trades
// regress (R6); 32-q blocks halve arithmetic intensity (R5).
__global__ __launch_bounds__(512, 4) void attn_kernel(
    const unsigned short* __restrict__ ft, const unsigned short* __restrict__ g,
    const unsigned short* __restrict__ h3, const float* __restrict__ x,
    const float* __restrict__ gamma_p, float* __restrict__ out)
{
    const int t    = threadIdx.x;
    const int b    = blockIdx.x & 7;          // batch -> XCD pin
    const int q0   = (blockIdx.x >> 3) * 64;
    const int lane = t & 63, w = t >> 6, l15 = lane & 15, quad = lane >> 4;
    const int qt_w = w >> 1, half = w & 1;

    __shared__ __align__(16) uint4 pB[2][2][4][64];   // [buf][half][qt][lane] 16 KB
    __shared__ float l_l[4][16][2];

    union { short8 v; unsigned short u[8]; } gfrag;   // B[k=quad*8+j][q=l15] of q-tile qt_w
    #pragma unroll
    for (int j = 0; j < 8; j++) {
        int k = quad*8 + j;
        gfrag.u[j] = (k < DQK) ? g[(size_t)(b*DQK + k)*HWN + q0 + qt_w*16 + l15] : (unsigned short)0;
    }

    const unsigned short* ftb = ft + (size_t)b*HWN*32;
    const unsigned short* h3b = h3 + ((size_t)b << 20);

    short8 fr[2][2], hr[2][2][2];
    float4v acc[2][4];
    #pragma unroll
    for (int i = 0; i < 2; i++)
        #pragma unroll
        for (int j = 0; j < 4; j++) acc[i][j] = (float4v){0.f,0.f,0.f,0.f};
    float l_acc = 0.f;
    uint4 P;

    // ---- prologue: fr tile0 -> slot0, S^T(0)+exp2 -> P, fr tile1 -> slot1,
    //      hr tile0 -> slot0 ----
    #pragma unroll
    for (int j = 0; j < 2; j++)
        fr[0][j] = *(const short8*)&ftb[(size_t)((half*2 + j)*16 + l15)*32 + quad*8];
    {
        float4v z = {0.f,0.f,0.f,0.f};
        float4v s0v = __builtin_amdgcn_mfma_f32_16x16x32_bf16(fr[0][0], gfrag.v, z, 0, 0, 0);
        float4v s1v = __builtin_amdgcn_mfma_f32_16x16x32_bf16(fr[0][1], gfrag.v, z, 0, 0, 0);
        float e0 = ex2(s0v[0]), e1 = ex2(s0v[1]), e2 = ex2(s0v[2]), e3 = ex2(s0v[3]);
        float e4 = ex2(s1v[0]), e5 = ex2(s1v[1]), e6 = ex2(s1v[2]), e7 = ex2(s1v[3]);
        l_acc += (e0 + e1) + (e2 + e3) + (e4 + e5) + (e6 + e7);
        P = make_uint4(cvtpk(e0, e1), cvtpk(e2, e3), cvtpk(e4, e5), cvtpk(e6, e7));
    }
    #pragma unroll
    for (int j = 0; j < 2; j++)
        fr[1][j] = *(const short8*)&ftb[(size_t)(64 + (half*2 + j)*16 + l15)*32 + quad*8];
    #pragma unroll
    for (int grp = 0; grp < 2; grp++)
        #pragma unroll
        for (int ctl = 0; ctl < 2; ctl++)
            hr[0][grp][ctl] = *(const short8*)&h3b[(((size_t)(grp*16 + w*2 + ctl)) << 9) + lane*8];

    // Per-iter i (buf u=i&1):
    //  1. hr prefetch tile i+1 -> hr[u^1]  (PRE-barrier; consumed in iter
    //     i+1's PV; same-wave WAR vs PV(i-1)'s read is program-order-safe)
    //  2. pB[u] write of P(i)  3. lgkm-barrier
    //  4. fr prefetch tile i+2 -> fr[u] (no wrap: slop reads stay in ws)
    //  5. S^T(i+1) from fr[u^1] + exp2 -> P
    //  6. PV(i) from hr[u], pB[u] under setprio(1)
    // pB[u] WAR-safe: last readers (iter i-2) consumed pre-barrier(i-1).
#define ATTN_STEP(u, i, DO_NEXT) do {                                          \
    if (DO_NEXT) {                                                             \
      const int nh = (i) + 1;                                                  \
      _Pragma("unroll")                                                        \
      for (int grp = 0; grp < 2; grp++)                                        \
        _Pragma("unroll")                                                      \
        for (int ctl = 0; ctl < 2; ctl++)                                      \
          hr[(u)^1][grp][ctl] = *(const short8*)&h3b[(((size_t)((nh*2 + grp)*16 + w*2 + ctl)) << 9) + lane*8]; \
    }                                                                          \
    pB[u][half][qt_w][lane] = P;                                               \
    lds_barrier();                                                             \
    if (DO_NEXT) {                                                             \
      const int nf = (i) + 2;                                                  \
      _Pragma("unroll")                                                        \
      for (int j = 0; j < 2; j++)                                              \
        fr[u][j] = *(const short8*)&ftb[(size_t)(nf*64 + (half*2 + j)*16 + l15)*32 + quad*8]; \
      float4v z = {0.f,0.f,0.f,0.f};                                           \
      float4v s0v = __builtin_amdgcn_mfma_f32_16x16x32_bf16(fr[(u)^1][0], gfrag.v, z, 0, 0, 0); \
      float4v s1v = __builtin_amdgcn_mfma_f32_16x16x32_bf16(fr[(u)^1][1], gfrag.v, z, 0, 0, 0); \
      float e0 = ex2(s0v[0]), e1 = ex2(s0v[1]), e2 = ex2(s0v[2]), e3 = ex2(s0v[3]); \
      float e4 = ex2(s1v[0]), e5 = ex2(s1v[1]), e6 = ex2(s1v[2]), e7 = ex2(s1v[3]); \
      l_acc += (e0 + e1) + (e2 + e3) + (e4 + e5) + (e6 + e7);                  \
      P = make_uint4(cvtpk(e0, e1), cvtpk(e2, e3), cvtpk(e4, e5), cvtpk(e6, e7)); \
    }                                                                          \
    __builtin_amdgcn_s_setprio(1);                                             \
    _Pragma("unroll")                                                          \
    for (int grp = 0; grp < 2; grp++) {                                        \
      _Pragma("unroll")                                                        \
      for (int qt = 0; qt < 4; qt++) {                                         \
        union { uint4 uu; short8 v; } bq;                                      \
        bq.uu = pB[u][grp][qt][lane];                                          \
        _Pragma("unroll")                                                      \
        for (int ctl = 0; ctl < 2; ctl++)                                      \
          acc[ctl][qt] = __builtin_amdgcn_mfma_f32_16x16x32_bf16(hr[u][grp][ctl], bq.v, acc[ctl][qt], 0, 0, 0); \
      }                                                                        \
    }                                                                          \
    __builtin_amdgcn_s_setprio(0);                                             \
  } while (0)

    // R12: quad-unroll -> compile-time tile offsets within each trip.
    for (int i0 = 0; i0 < 60; i0 += 4) {
        ATTN_STEP(0, i0 + 0, 1);
        ATTN_STEP(1, i0 + 1, 1);
        ATTN_STEP(0, i0 + 2, 1);
        ATTN_STEP(1, i0 + 3, 1);
    }
    ATTN_STEP(0, 60, 1);
    ATTN_STEP(1, 61, 1);
    ATTN_STEP(0, 62, 1);   // computes S^T(63)+P; fr prefetch (tile 64) is dead slop
    ATTN_STEP(1, 63, 0);   // peeled tail: write P(63), PV(63) only
#undef ATTN_STEP

    // ---- l: reduce over quads; combine halves via LDS ----
    l_acc += __shfl_xor(l_acc, 16, 64);
    l_acc += __shfl_xor(l_acc, 32, 64);
    if (quad == 0) l_l[qt_w][l15][half] = l_acc;
    __syncthreads();

    const float gamma = *gamma_p;
    float linv[4];
    #pragma unroll
    for (int qt = 0; qt < 4; qt++) linv[qt] = 1.f / (l_l[qt][l15][0] + l_l[qt][l15][1]);
    #pragma unroll
    for (int ctl = 0; ctl < 2; ctl++) {
        #pragma unroll
        for (int r = 0; r < 4; r++) {
            int c = w*32 + ctl*16 + quad*4 + r;
            size_t base = (size_t)(b*CH + c)*HWN + q0;
            #pragma unroll
            for (int qt = 0; qt < 4; qt++) {
                size_t o = base + qt*16 + l15;
                out[o] = gamma * acc[ctl][qt][r] * linv[qt] + x[o];
            }
        }
    }
}

extern "C" void kernel_launch(void* const* d_in, const int* in_sizes, int n_in,
                              void* d_out, int out_size, void* d_ws, size_t ws_size,
                              hipStream_t stream) {
    const float* x     = (const float*)d_in[0];
    const float* Wf    = (const float*)d_in[1];
    const float* bf_   = (const float*)d_in[2];
    const float* Wg    = (const float*)d_in[3];
    const float* bg    = (const float*)d_in[4];
    const float* Wh    = (const float*)d_in[5];
    const float* bh    = (const float*)d_in[6];
    const float* gamma = (const float*)d_in[7];
    float* out = (float*)d_out;

    // ws: ft 2MB | g 1MB | h3 16.8MB | Wbf 147KB | bcat  (xt eliminated)
    unsigned short* ftp  = (unsigned short*)d_ws;
    unsigned short* g    = ftp + (size_t)BATCH*HWN*32;
    unsigned short* h3   = g   + (size_t)BATCH*DQK*HWN;
    unsigned short* Wbf  = h3  + (size_t)BATCH*128*16*512;
    float*          bcat = (float*)(Wbf + 288*CH);

    wcast_kernel<<<dim3(288), 256, 0, stream>>>(Wf, bf_, Wg, bg, Wh, bh, Wbf, bcat);
    proj_kernel<<<dim3(HWN/32, BATCH), 256, 0, stream>>>(x, Wbf, bcat, ftp, g, h3);
    attn_kernel<<<dim3((HWN/64)*BATCH), 512, 0, stream>>>(ftp, g, h3, x, gamma, out);
}

// Round 13
// 203.622 us; speedup vs baseline: 1.1188x; 1.1188x over previous
//
#include <hip/hip_runtime.h>
#include <math.h>

#define BATCH 8
#define CH    256
#define HWN   4096
#define DQK   16

typedef __attribute__((ext_vector_type(8))) short short8;
typedef __attribute__((ext_vector_type(4))) float float4v;

#define L2E 1.4426950408889634f

__device__ __forceinline__ unsigned short f2bf(float f) {
    union { float f; unsigned int u; } v; v.f = f;
    unsigned int r = v.u + 0x7FFF + ((v.u >> 16) & 1);   // RNE
    return (unsigned short)(r >> 16);
}
// HW packed f32->bf16 convert (RNE): %1 -> low16, %2 -> high16
__device__ __forceinline__ unsigned int cvtpk(float lo, float hi) {
    unsigned int r;
    asm("v_cvt_pk_bf16_f32 %0, %1, %2" : "=v"(r) : "v"(lo), "v"(hi));
    return r;
}
// 2^x via hardware v_exp_f32, compiler-managed TRANS hazards
__device__ __forceinline__ float ex2(float x) {
#if __has_builtin(__builtin_amdgcn_exp2f)
    return __builtin_amdgcn_exp2f(x);
#else
    return exp2f(x);
#endif
}
// Block barrier WITHOUT the vmcnt(0) drain __syncthreads carries (T4):
// only LDS ordering is required for the pB exchange; global prefetches
// stay in flight across the barrier.
__device__ __forceinline__ void lds_barrier() {
    asm volatile("s_waitcnt lgkmcnt(0)" ::: "memory");
    __builtin_amdgcn_s_barrier();
}
// ft row permutation: stored row s holds key m with s4=m2, s3=m4, s2=m3
// (bits 0,1,5+ unchanged). Makes S^T output registers align with PV B-frag
// slots in the SAME lane (no cross-lane transpose needed).
__device__ __forceinline__ int perm_ft(int m) {
    return (m & ~28) | ((m & 24) >> 1) | ((m & 4) << 2);
}

// ---------------- kernel 0: W_cat -> bf16, biases -> bcat ----------------
__global__ __launch_bounds__(256) void wcast_kernel(
    const float* __restrict__ Wf, const float* __restrict__ bf_,
    const float* __restrict__ Wg, const float* __restrict__ bg,
    const float* __restrict__ Wh, const float* __restrict__ bh,
    unsigned short* __restrict__ Wbf, float* __restrict__ bcat)
{
    const int r = blockIdx.x;   // 288 rows
    const int t = threadIdx.x;  // 256 cols
    const float* src = (r < 16) ? (Wf + r*CH) : (r < 32) ? (Wg + (r-16)*CH) : (Wh + (r-32)*CH);
    Wbf[r*CH + t] = f2bf(src[t]);
    if (t == 0) bcat[r] = (r < 16) ? bf_[r] : (r < 32) ? bg[r-16] : bh[r-32];
}

// ---------------- kernel 1: FUSED transpose + MFMA projection ----------------
// R11 design: kills the xt tensor (was 134 MB read + 67 MB write + 33.5 MB
// re-read). Block = 32 px x 256 c, grid (128, 8) = 1024 blocks (4/CU).
// Stage x[b][*][px0..31] -> LDS tile[32][264] bf16 (float4 loads over px,
// cvt_pk; rows 16B-aligned). One barrier. Wave split covers all 18 W_cat
// rows in one pass over x: wave w -> rt-group (w>>1)*9, px-half (w&1)*16.
// acc 9x4 = 36 AGPR; ~80 regs total, no spill.
// Epilogue: ft at perm_ft rows PRE-SCALED by log2e; g; h3 frag layout.
__global__ __launch_bounds__(256, 4) void proj_kernel(
    const float* __restrict__ x, const unsigned short* __restrict__ Wbf,
    const float* __restrict__ bcat,
    unsigned short* __restrict__ ft, unsigned short* __restrict__ g,
    unsigned short* __restrict__ h3)
{
    const int t    = threadIdx.x;
    const int px0  = blockIdx.x * 32;
    const int b    = blockIdx.y;
    const int lane = t & 63, w = t >> 6, l15 = lane & 15, quad = lane >> 4;
    const int rtbase = (w >> 1) * 9;      // 0 or 9
    const int pxh    = (w & 1) * 16;      // px-half within the 32-px tile

    __shared__ unsigned short tile[32][264];   // 16.5 KB, rows 16B-aligned

    // ---- stage: x[b][c][px0+px4 .. +3] -> tile[px][c] ----
    const int px4 = (t & 7) * 4;          // 0..28
    const int c0  = t >> 3;               // 0..31
    #pragma unroll
    for (int j = 0; j < 8; j++) {
        int c = c0 + j*32;
        float4 v = *(const float4*)&x[(size_t)(b*CH + c)*HWN + px0 + px4];
        unsigned int u01 = cvtpk(v.x, v.y), u23 = cvtpk(v.z, v.w);
        tile[px4+0][c] = (unsigned short)u01;
        tile[px4+1][c] = (unsigned short)(u01 >> 16);
        tile[px4+2][c] = (unsigned short)u23;
        tile[px4+3][c] = (unsigned short)(u23 >> 16);
    }
    __syncthreads();

    float4v acc[9];
    #pragma unroll
    for (int rt = 0; rt < 9; rt++) acc[rt] = (float4v){0.f,0.f,0.f,0.f};

    const unsigned short* wrow = &Wbf[(size_t)l15*CH + quad*8];

    #pragma unroll
    for (int ks = 0; ks < 8; ks++) {
        short8 afrag = *(const short8*)&tile[pxh + l15][quad*8 + ks*32];
        #pragma unroll
        for (int rt = 0; rt < 9; rt++) {
            short8 bfrag = *(const short8*)&wrow[(size_t)(rtbase + rt)*16*CH + ks*32];
            acc[rt] = __builtin_amdgcn_mfma_f32_16x16x32_bf16(afrag, bfrag, acc[rt], 0, 0, 0);
        }
    }

    const int pxl = px0 + pxh + quad*4;   // this lane's px base (+r)
    const int mt  = px0 >> 5;             // = blockIdx.x
    const int sub = ((w & 1)*2 + (quad >> 1))*128 + l15*8 + (quad & 1)*4;
    #pragma unroll
    for (int rt = 0; rt < 9; rt++) {
        const int R = rtbase + rt;        // uniform per wave
        if (R == 0) {                     // -> ft at perm_ft rows, * log2e
            float bv = bcat[l15];
            const int s0 = perm_ft(pxl);  // r only touches bits 0,1
            unsigned int p01 = cvtpk((acc[rt][0] + bv)*L2E, (acc[rt][1] + bv)*L2E);
            unsigned int p23 = cvtpk((acc[rt][2] + bv)*L2E, (acc[rt][3] + bv)*L2E);
            unsigned short* fp0 = &ft[((size_t)b*HWN + s0)*32];
            fp0[l15]       = (unsigned short)p01;         fp0[16 + l15]  = 0;
            fp0[32 + l15]  = (unsigned short)(p01 >> 16); fp0[48 + l15]  = 0;
            fp0[64 + l15]  = (unsigned short)p23;         fp0[80 + l15]  = 0;
            fp0[96 + l15]  = (unsigned short)(p23 >> 16); fp0[112 + l15] = 0;
        } else if (R == 1) {              // -> g (4 consecutive px: uint2)
            float bv = bcat[16 + l15];
            unsigned int a01 = cvtpk(acc[rt][0] + bv, acc[rt][1] + bv);
            unsigned int a23 = cvtpk(acc[rt][2] + bv, acc[rt][3] + bv);
            *(uint2*)&g[(size_t)(b*DQK + l15)*HWN + pxl] = make_uint2(a01, a23);
        } else {                          // -> h3 frag layout
            float bv = bcat[R*16 + l15];
            unsigned int u0 = cvtpk(acc[rt][0] + bv, acc[rt][1] + bv);
            unsigned int u1 = cvtpk(acc[rt][2] + bv, acc[rt][3] + bv);
            *(uint2*)&h3[(((size_t)((b*128 + mt)*16 + (R-2))) << 9) + sub] = make_uint2(u0, u1);
        }
    }
}

// ---------------- kernel 2: MFMA flash attention, 8 waves ----------------
// FINAL: R7 structure (best measured: 86.0-86.8 us, VGPR 60, no spill).
// Block = 512 thr, (batch, 64-q tile), grid 512. 1 key-tile/barrier, pB[2]
// dbuf, software pipeline (P(i+1) computed during PV(i)), lgkm-only
// barrier (no vmcnt drain), pre-barrier hr prefetch, exp2 on L2E-prescaled
// ft, cvt_pk packing, setprio around PV.
// Closed directions (all measured this session):
//  - >96 live VGPRs + 32 AGPR spills at this occupancy (R3/R8/R9/R12);
//    2-step unroll is the max this structure tolerates (R12: quad -> spill)
//  - trading pB LDS reads for extra L2 loads regresses (R6: L2 BW is the
//    scarcer resource at ~23 TB/s vs 34.5 ceiling)
//  - 32-q blocks halve arithmetic intensity vs ft/h3 streams (R5)
//  - sched_barrier(0) prefetch pinning forces spill (R8)
__global__ __launch_bounds__(512, 4) void attn_kernel(
    const unsigned short* __restrict__ ft, const unsigned short* __restrict__ g,
    const unsigned short* __restrict__ h3, const float* __restrict__ x,
    const float* __restrict__ gamma_p, float* __restrict__ out)
{
    const int t    = threadIdx.x;
    const int b    = blockIdx.x & 7;          // batch -> XCD pin
    const int q0   = (blockIdx.x >> 3) * 64;
    const int lane = t & 63, w = t >> 6, l15 = lane & 15, quad = lane >> 4;
    const int qt_w = w >> 1, half = w & 1;

    __shared__ __align__(16) uint4 pB[2][2][4][64];   // [buf][half][qt][lane] 16 KB
    __shared__ float l_l[4][16][2];

    union { short8 v; unsigned short u[8]; } gfrag;   // B[k=quad*8+j][q=l15] of q-tile qt_w
    #pragma unroll
    for (int j = 0; j < 8; j++) {
        int k = quad*8 + j;
        gfrag.u[j] = (k < DQK) ? g[(size_t)(b*DQK + k)*HWN + q0 + qt_w*16 + l15] : (unsigned short)0;
    }

    const unsigned short* ftb = ft + (size_t)b*HWN*32;
    const unsigned short* h3b = h3 + ((size_t)b << 20);

    short8 fr[2][2], hr[2][2][2];
    float4v acc[2][4];
    #pragma unroll
    for (int i = 0; i < 2; i++)
        #pragma unroll
        for (int j = 0; j < 4; j++) acc[i][j] = (float4v){0.f,0.f,0.f,0.f};
    float l_acc = 0.f;
    uint4 P;

    // ---- prologue: fr tile0 -> slot0, S^T(0)+exp2 -> P, fr tile1 -> slot1,
    //      hr tile0 -> slot0 ----
    #pragma unroll
    for (int j = 0; j < 2; j++)
        fr[0][j] = *(const short8*)&ftb[(size_t)((half*2 + j)*16 + l15)*32 + quad*8];
    {
        float4v z = {0.f,0.f,0.f,0.f};
        float4v s0v = __builtin_amdgcn_mfma_f32_16x16x32_bf16(fr[0][0], gfrag.v, z, 0, 0, 0);
        float4v s1v = __builtin_amdgcn_mfma_f32_16x16x32_bf16(fr[0][1], gfrag.v, z, 0, 0, 0);
        float e0 = ex2(s0v[0]), e1 = ex2(s0v[1]), e2 = ex2(s0v[2]), e3 = ex2(s0v[3]);
        float e4 = ex2(s1v[0]), e5 = ex2(s1v[1]), e6 = ex2(s1v[2]), e7 = ex2(s1v[3]);
        l_acc += (e0 + e1) + (e2 + e3) + (e4 + e5) + (e6 + e7);
        P = make_uint4(cvtpk(e0, e1), cvtpk(e2, e3), cvtpk(e4, e5), cvtpk(e6, e7));
    }
    #pragma unroll
    for (int j = 0; j < 2; j++)
        fr[1][j] = *(const short8*)&ftb[(size_t)(64 + (half*2 + j)*16 + l15)*32 + quad*8];
    #pragma unroll
    for (int grp = 0; grp < 2; grp++)
        #pragma unroll
        for (int ctl = 0; ctl < 2; ctl++)
            hr[0][grp][ctl] = *(const short8*)&h3b[(((size_t)(grp*16 + w*2 + ctl)) << 9) + lane*8];

    // Per-iter i (buf u=i&1):
    //  1. hr prefetch tile i+1 -> hr[u^1]  (PRE-barrier; consumed in iter
    //     i+1's PV; same-wave WAR vs PV(i-1)'s read is program-order-safe)
    //  2. pB[u] write of P(i)  3. lgkm-barrier
    //  4. fr prefetch tile i+2 -> fr[u] (no wrap: slop reads stay in ws)
    //  5. S^T(i+1) from fr[u^1] + exp2 -> P
    //  6. PV(i) from hr[u], pB[u] under setprio(1)
    // pB[u] WAR-safe: last readers (iter i-2) consumed pre-barrier(i-1).
#define ATTN_STEP(u, i, DO_NEXT) do {                                          \
    if (DO_NEXT) {                                                             \
      const int nh = (i) + 1;                                                  \
      _Pragma("unroll")                                                        \
      for (int grp = 0; grp < 2; grp++)                                        \
        _Pragma("unroll")                                                      \
        for (int ctl = 0; ctl < 2; ctl++)                                      \
          hr[(u)^1][grp][ctl] = *(const short8*)&h3b[(((size_t)((nh*2 + grp)*16 + w*2 + ctl)) << 9) + lane*8]; \
    }                                                                          \
    pB[u][half][qt_w][lane] = P;                                               \
    lds_barrier();                                                             \
    if (DO_NEXT) {                                                             \
      const int nf = (i) + 2;                                                  \
      _Pragma("unroll")                                                        \
      for (int j = 0; j < 2; j++)                                              \
        fr[u][j] = *(const short8*)&ftb[(size_t)(nf*64 + (half*2 + j)*16 + l15)*32 + quad*8]; \
      float4v z = {0.f,0.f,0.f,0.f};                                           \
      float4v s0v = __builtin_amdgcn_mfma_f32_16x16x32_bf16(fr[(u)^1][0], gfrag.v, z, 0, 0, 0); \
      float4v s1v = __builtin_amdgcn_mfma_f32_16x16x32_bf16(fr[(u)^1][1], gfrag.v, z, 0, 0, 0); \
      float e0 = ex2(s0v[0]), e1 = ex2(s0v[1]), e2 = ex2(s0v[2]), e3 = ex2(s0v[3]); \
      float e4 = ex2(s1v[0]), e5 = ex2(s1v[1]), e6 = ex2(s1v[2]), e7 = ex2(s1v[3]); \
      l_acc += (e0 + e1) + (e2 + e3) + (e4 + e5) + (e6 + e7);                  \
      P = make_uint4(cvtpk(e0, e1), cvtpk(e2, e3), cvtpk(e4, e5), cvtpk(e6, e7)); \
    }                                                                          \
    __builtin_amdgcn_s_setprio(1);                                             \
    _Pragma("unroll")                                                          \
    for (int grp = 0; grp < 2; grp++) {                                        \
      _Pragma("unroll")                                                        \
      for (int qt = 0; qt < 4; qt++) {                                         \
        union { uint4 uu; short8 v; } bq;                                      \
        bq.uu = pB[u][grp][qt][lane];                                          \
        _Pragma("unroll")                                                      \
        for (int ctl = 0; ctl < 2; ctl++)                                      \
          acc[ctl][qt] = __builtin_amdgcn_mfma_f32_16x16x32_bf16(hr[u][grp][ctl], bq.v, acc[ctl][qt], 0, 0, 0); \
      }                                                                        \
    }                                                                          \
    __builtin_amdgcn_s_setprio(0);                                             \
  } while (0)

    for (int i0 = 0; i0 < 62; i0 += 2) {
        ATTN_STEP(0, i0, 1);
        ATTN_STEP(1, i0 + 1, 1);
    }
    ATTN_STEP(0, 62, 1);   // computes S^T(63)+P; fr prefetch (tile 64) is dead slop
    ATTN_STEP(1, 63, 0);   // peeled tail: write P(63), PV(63) only
#undef ATTN_STEP

    // ---- l: reduce over quads; combine halves via LDS ----
    l_acc += __shfl_xor(l_acc, 16, 64);
    l_acc += __shfl_xor(l_acc, 32, 64);
    if (quad == 0) l_l[qt_w][l15][half] = l_acc;
    __syncthreads();

    const float gamma = *gamma_p;
    float linv[4];
    #pragma unroll
    for (int qt = 0; qt < 4; qt++) linv[qt] = 1.f / (l_l[qt][l15][0] + l_l[qt][l15][1]);
    #pragma unroll
    for (int ctl = 0; ctl < 2; ctl++) {
        #pragma unroll
        for (int r = 0; r < 4; r++) {
            int c = w*32 + ctl*16 + quad*4 + r;
            size_t base = (size_t)(b*CH + c)*HWN + q0;
            #pragma unroll
            for (int qt = 0; qt < 4; qt++) {
                size_t o = base + qt*16 + l15;
                out[o] = gamma * acc[ctl][qt][r] * linv[qt] + x[o];
            }
        }
    }
}

extern "C" void kernel_launch(void* const* d_in, const int* in_sizes, int n_in,
                              void* d_out, int out_size, void* d_ws, size_t ws_size,
                              hipStream_t stream) {
    const float* x     = (const float*)d_in[0];
    const float* Wf    = (const float*)d_in[1];
    const float* bf_   = (const float*)d_in[2];
    const float* Wg    = (const float*)d_in[3];
    const float* bg    = (const float*)d_in[4];
    const float* Wh    = (const float*)d_in[5];
    const float* bh    = (const float*)d_in[6];
    const float* gamma = (const float*)d_in[7];
    float* out = (float*)d_out;

    // ws: ft 2MB | g 1MB | h3 16.8MB | Wbf 147KB | bcat  (xt eliminated)
    unsigned short* ftp  = (unsigned short*)d_ws;
    unsigned short* g    = ftp + (size_t)BATCH*HWN*32;
    unsigned short* h3   = g   + (size_t)BATCH*DQK*HWN;
    unsigned short* Wbf  = h3  + (size_t)BATCH*128*16*512;
    float*          bcat = (float*)(Wbf + 288*CH);

    wcast_kernel<<<dim3(288), 256, 0, stream>>>(Wf, bf_, Wg, bg, Wh, bh, Wbf, bcat);
    proj_kernel<<<dim3(HWN/32, BATCH), 256, 0, stream>>>(x, Wbf, bcat, ftp, g, h3);
    attn_kernel<<<dim3((HWN/64)*BATCH), 512, 0, stream>>>(ftp, g, h3, x, gamma, out);
}